// Round 12
// baseline (127.230 us; speedup 1.0000x reference)
//
#include <hip/hip_runtime.h>
#include <math.h>

#define BB 4
#define TT 4096
#define CC 1024
#define HS 64
#define MM (BB*TT)   // 16384
#define KSPLIT 8

typedef __attribute__((ext_vector_type(8))) short short8;    // 8 bf16 (4 VGPR)
typedef __attribute__((ext_vector_type(4))) float f32x4;     // MFMA acc
typedef __attribute__((ext_vector_type(4))) unsigned short ushort4v;

__device__ __forceinline__ unsigned short f2bf(float f) {   // RNE fp32->bf16
    union { float f; unsigned u; } v; v.f = f;
    return (unsigned short)((v.u + 0x7fffu + ((v.u >> 16) & 1u)) >> 16);
}

// packed RNE fp32x2 -> bf16x2 (bit-identical to f2bf for finite values)
__device__ __forceinline__ unsigned cvt_pk_bf16(float lo, float hi) {
    unsigned r;
    asm("v_cvt_pk_bf16_f32 %0, %1, %2" : "=v"(r) : "v"(lo), "v"(hi));
    return r;
}

// async global->LDS DMA, 16B per lane; LDS dest = wave-uniform base + lane*16
typedef __attribute__((address_space(3))) unsigned short lds_us;
typedef __attribute__((address_space(1))) const unsigned short glb_us;
__device__ __forceinline__ void g2lds16(const unsigned short* g, unsigned short* l) {
    __builtin_amdgcn_global_load_lds((glb_us*)g, (lds_us*)l, 16, 0, 0);
}

// V key-position permutation for the permlane-repacked PV A-fragment.
__device__ __forceinline__ int g4pos(int k) {
    return (k & 32) + 8 * (2 * ((k >> 4) & 1) + ((k >> 2) & 1)) + 4 * ((k >> 3) & 1);
}

// ---------------------------------------------------------------------------
// prep: Wt = W^T bf16, PRE-SWIZZLED + chunk-linearized for qkv's global_load_lds
// (unchanged). Wq pre-scaled by 0.125.
// ---------------------------------------------------------------------------
__global__ __launch_bounds__(256) void prep_kernel(
    const float* __restrict__ Wq, const float* __restrict__ Wk,
    const float* __restrict__ Wv, unsigned short* __restrict__ Wt)
{
    const int which = blockIdx.x >> 4;
    const int k0 = (blockIdx.x & 15) * 64;
    const float* __restrict__ W = (which == 0) ? Wq : (which == 1) ? Wk : Wv;
    const float scale = (which == 0) ? 0.125f : 1.0f;
    __shared__ unsigned short lds[64][65];
    const int t = threadIdx.x;
    #pragma unroll
    for (int i = 0; i < 16; i++) {
        int idx = t + 256 * i;
        int r = idx >> 6, n = idx & 63;           // coalesced read (n fast)
        lds[r][n] = f2bf(W[(size_t)(k0 + r) * 64 + n] * scale);
    }
    __syncthreads();
    #pragma unroll
    for (int i = 0; i < 16; i++) {
        int idx = t + 256 * i;
        int n = idx >> 6, r = idx & 63;           // coalesced write (k fast)
        int nrow = which * 64 + n;
        int kg = k0 + r;
        int ck = kg >> 7, kloc = kg & 127;
        Wt[(size_t)ck * 24576 + (((nrow << 7) + kloc) ^ ((nrow & 7) << 3))] = lds[r][n];
    }
}

// ---------------------------------------------------------------------------
// qkv_mfma: unchanged from R11. q stored pre-scaled by log2(e); K/V emitted
// tile-major + pre-swizzled (+g4pos-permuted V) for attn's DMA staging.
// ---------------------------------------------------------------------------
__global__ __launch_bounds__(256, 2) void qkv_mfma(
    const float* __restrict__ x, const unsigned short* __restrict__ Wt,
    unsigned short* __restrict__ qb, unsigned short* __restrict__ kbt,
    unsigned short* __restrict__ vTt)
{
    const int rt = blockIdx.x;                 // 32-row tile, 512 blocks
    __shared__ __align__(16) unsigned short xs[32][136];   // padded, reg-staged
    __shared__ __align__(16) unsigned short wsf[192 * 128]; // linear, DMA'd (48KB)

    const int t = threadIdx.x;
    const int w = t >> 6;
    const int lane = t & 63;
    const int quad = lane >> 4;
    const int c = lane & 15;

    const int c2x32 = ((c >> 2) & 1) << 5;     // swizzle: ks-bit flip (in shorts)
    const int quad2 = quad ^ (c & 3);          // swizzle: quad permute

    float4 xreg[4];
    #pragma unroll
    for (int i = 0; i < 4; i++) {              // chunk 0 x
        int idx = t + 256 * i;
        int r = idx >> 5, c4 = (idx & 31) * 4;
        xreg[i] = *(const float4*)(x + (size_t)(rt * 32 + r) * CC + c4);
    }

    f32x4 acc[2][3];
    #pragma unroll
    for (int mt = 0; mt < 2; mt++)
        #pragma unroll
        for (int j = 0; j < 3; j++) acc[mt][j] = (f32x4){0.f, 0.f, 0.f, 0.f};

    for (int ck = 0; ck < 8; ++ck) {
        __syncthreads();                       // prev compute done reading xs/wsf
        // W chunk: 12 x 4KB async DMA (48KB), linear dest, pre-swizzled source
        {
            const unsigned short* wgp = Wt + (size_t)ck * 24576 + t * 8;
            #pragma unroll
            for (int i = 0; i < 12; i++)
                g2lds16(wgp + i * 2048, wsf + (i * 256 + w * 64) * 8);
        }
        // stage x (from regs loaded during previous compute phase)
        #pragma unroll
        for (int i = 0; i < 4; i++) {
            int idx = t + 256 * i;
            int r = idx >> 5, c4 = (idx & 31) * 4;
            ushort4v p = { f2bf(xreg[i].x), f2bf(xreg[i].y), f2bf(xreg[i].z), f2bf(xreg[i].w) };
            *(ushort4v*)&xs[r][c4] = p;
        }
        __syncthreads();                       // drains W DMA + x ds-writes

        // next-chunk x load: issued at top of compute, drains at next barrier
        if (ck + 1 < 8) {
            #pragma unroll
            for (int i = 0; i < 4; i++) {
                int idx = t + 256 * i;
                int r = idx >> 5, c4 = (idx & 31) * 4;
                xreg[i] = *(const float4*)(x + (size_t)(rt * 32 + r) * CC + (ck + 1) * 128 + c4);
            }
        }

        #pragma unroll
        for (int ks = 0; ks < 4; ks++) {
            short8 af[2], bf[3];
            #pragma unroll
            for (int mt = 0; mt < 2; mt++)
                af[mt] = *(const short8*)&xs[16 * mt + c][ks * 32 + quad * 8];
            #pragma unroll
            for (int j = 0; j < 3; j++)
                bf[j] = *(const short8*)&wsf[(16 * (w + 4 * j) + c) * 128 +
                                             ((ks * 32) ^ c2x32) + quad2 * 8];
            #pragma unroll
            for (int mt = 0; mt < 2; mt++)
                #pragma unroll
                for (int j = 0; j < 3; j++)
                    acc[mt][j] = __builtin_amdgcn_mfma_f32_16x16x32_bf16(af[mt], bf[j], acc[mt][j], 0, 0, 0);
        }
    }

    // epilogue: q (x log2e) direct; k -> tiled+swizzled kbt; v -> transposed vTt
    __syncthreads();
    const int b  = rt >> 7;                    // batch
    unsigned short (*vtb)[72] = (unsigned short (*)[72])wsf;  // [d 0..63][t-local 0..31]
    #pragma unroll
    for (int mt = 0; mt < 2; mt++) {
        int grow = rt * 32 + 16 * mt + quad * 4;
        #pragma unroll
        for (int reg = 0; reg < 4; reg++) {
            int trow = grow + reg;                     // global row
            qb[(size_t)trow * HS + 16 * w + c] = f2bf(acc[mt][0][reg] * 1.4426950408889634f);
            int tin = trow & 4095;                     // row within batch
            int kt = tin >> 6, kl = tin & 63;
            int dcol = 16 * w + c;
            kbt[(size_t)(b * 64 + kt) * 4096 + kl * 64 + (dcol ^ ((kl & 7) << 3))]
                = f2bf(acc[mt][1][reg]);
            vtb[16 * w + c][16 * mt + quad * 4 + reg] = f2bf(acc[mt][2][reg]);
        }
    }
    __syncthreads();
    {
        const int t0 = (rt & 127) * 32;
        const int kt = t0 >> 6, half = (t0 >> 5) & 1;
        int d = t >> 2, c8 = (t & 3) * 8;
        short8 v0 = *(const short8*)&vtb[d][c8];
        unsigned short* base = vTt + (size_t)(b * 64 + kt) * 4096 + d * 64;
        const int kl0 = half * 32 + c8;                 // first key of the 8
        const int p0 = g4pos(kl0), p1 = g4pos(kl0 + 4); // permuted positions
        ushort4v lo = { (unsigned short)v0[0], (unsigned short)v0[1],
                        (unsigned short)v0[2], (unsigned short)v0[3] };
        ushort4v hi = { (unsigned short)v0[4], (unsigned short)v0[5],
                        (unsigned short)v0[6], (unsigned short)v0[7] };
        *(ushort4v*)(base + (p0 ^ ((d & 7) << 3))) = lo;
        *(ushort4v*)(base + (p1 ^ ((d & 7) << 3))) = hi;
    }
}

// ---------------------------------------------------------------------------
// attn_mfma: R12 = R8's QT=256 done WITH occupancy preserved: 512-thread
// blocks (8 waves x 32 q-rows), grid 512 = 2 blocks/CU = 16 waves/CU
// (UNCHANGED from R11; R8's regression was 8 waves/CU, not the tile size).
// Per-wave register state and inner loop byte-identical to R11 (2 m-frags,
// <=128 VGPR at launch_bounds(512,4)). Effect: each staged 64-key tile now
// serves 256 q-rows -> staged-tile count, K/V DMA bytes (67.6->34.8 MB),
// barrier-drain events (4224->2176), and stage-issue ALL HALVE. STAGE is now
// 2 DMA instr/thread (512 threads cover the 8KB tile). 2-slot balanced map:
// CU k gets qt=(15-k/32) and qt=(k/32), qt-sum == 15 exact.
// Output BIT-IDENTICAL to R11 (same rows, same j-partition, same math order).
// ---------------------------------------------------------------------------
__global__ __launch_bounds__(512, 4) void attn_mfma(
    const unsigned short* __restrict__ qb, const unsigned short* __restrict__ kbt,
    const unsigned short* __restrict__ vTt, unsigned short* __restrict__ Opart,
    float* __restrict__ lpart)
{
    const int bid = blockIdx.x;                  // 512 = 16 p x 8 j x 4 b
    const int p   = bid >> 5;                    // dispatch-order qt-group
    const int qt  = (p < 8) ? (15 - p) : (p - 8);   // 2-slot balanced map
    const int rem = bid & 31;
    const int j   = rem >> 2;                    // K-split index 0..7
    const int b   = rem & 3;

    __shared__ __align__(16) unsigned short kv[2][2][4096]; // [buf][K/V][tile] 32 KB

    const int t = threadIdx.x;
    const int w = t >> 6;                       // 0..7
    const int lane = t & 63;
    const int quad = lane >> 4;
    const int c = lane & 15;
    const int qrow = qt * 256 + 32 * w;        // wave's first query row

    // swizzled column offsets for frag reads (row&7 == c&7 for all frag rows)
    const int csw0 = (quad * 8) ^ ((c & 7) << 3);
    const int csw1 = (32 + quad * 8) ^ ((c & 7) << 3);

    // Q frags resident in registers: 2 m-frags x 2 d-halves (used as B operand)
    short8 aq[2][2];
    #pragma unroll
    for (int mt = 0; mt < 2; mt++)
        #pragma unroll
        for (int kstep = 0; kstep < 2; kstep++)
            aq[mt][kstep] = *(const short8*)(qb + (size_t)(b * TT + qrow + 16 * mt + c) * HS + kstep * 32 + quad * 8);

    const int lastkt = 4 * qt + 3;             // last key-tile with any work
    const int nkt = (lastkt >= j) ? ((lastkt - j) / KSPLIT) + 1 : 0;
    const unsigned short* Ktiles = kbt + (size_t)b * 64 * 4096;
    const unsigned short* Vtiles = vTt + (size_t)b * 64 * 4096;

// 2 linear 8KB DMA strips (512 threads x 16B): whole K-tile + V-tile
#define STAGE(BUF, KT) do { \
    size_t o_ = (size_t)(KT) * 4096 + t * 8; \
    g2lds16(Ktiles + o_, &kv[BUF][0][w * 512]); \
    g2lds16(Vtiles + o_, &kv[BUF][1][w * 512]); } while (0)

    float l[2] = {0.f, 0.f};
    f32x4 oacc[2][4];
    #pragma unroll
    for (int mt = 0; mt < 2; mt++)
        #pragma unroll
        for (int dt = 0; dt < 4; dt++) oacc[mt][dt] = (f32x4){0.f, 0.f, 0.f, 0.f};

// Full tile: swapped QK^T -> masked exp2 -> in-register repack -> PV.
// S^T layout: lane(quad,c) reg r of s4[mt][st] = S[key=kt0+16st+4quad+r][q=qrow+16mt+c]
#define TILE(CB, DOMASK) do { \
    f32x4 s4[2][4]; \
    _Pragma("unroll") \
    for (int mt_ = 0; mt_ < 2; mt_++) \
        _Pragma("unroll") \
        for (int st_ = 0; st_ < 4; st_++) s4[mt_][st_] = (f32x4){0.f,0.f,0.f,0.f}; \
    _Pragma("unroll") \
    for (int st_ = 0; st_ < 4; st_++) { \
        short8 bf0 = *(const short8*)&kv[CB][0][(16 * st_ + c) * 64 + csw0]; \
        short8 bf1 = *(const short8*)&kv[CB][0][(16 * st_ + c) * 64 + csw1]; \
        __builtin_amdgcn_s_setprio(1); \
        s4[0][st_] = __builtin_amdgcn_mfma_f32_16x16x32_bf16(bf0, aq[0][0], s4[0][st_], 0, 0, 0); \
        s4[1][st_] = __builtin_amdgcn_mfma_f32_16x16x32_bf16(bf0, aq[1][0], s4[1][st_], 0, 0, 0); \
        s4[0][st_] = __builtin_amdgcn_mfma_f32_16x16x32_bf16(bf1, aq[0][1], s4[0][st_], 0, 0, 0); \
        s4[1][st_] = __builtin_amdgcn_mfma_f32_16x16x32_bf16(bf1, aq[1][1], s4[1][st_], 0, 0, 0); \
        __builtin_amdgcn_s_setprio(0); \
    } \
    short8 ap[2][2]; \
    _Pragma("unroll") \
    for (int mt_ = 0; mt_ < 2; mt_++) { \
        const int qg_ = qrow + 16 * mt_ + c; (void)qg_; \
        unsigned Wp[4][2]; \
        _Pragma("unroll") \
        for (int st_ = 0; st_ < 4; st_++) { \
            float pv_[4]; \
            _Pragma("unroll") \
            for (int r_ = 0; r_ < 4; r_++) { \
                float e_ = __builtin_amdgcn_exp2f(s4[mt_][st_][r_]); \
                if (DOMASK) { \
                    int kg_ = kt0 + 16 * st_ + 4 * quad + r_; \
                    if (kg_ > qg_) e_ = 0.f; \
                } \
                pv_[r_] = e_; l[mt_] += e_; \
            } \
            Wp[st_][0] = cvt_pk_bf16(pv_[0], pv_[1]); \
            Wp[st_][1] = cvt_pk_bf16(pv_[2], pv_[3]); \
        } \
        asm volatile("s_nop 1\nv_permlane32_swap_b32 %0, %1\ns_nop 1" : "+v"(Wp[0][0]), "+v"(Wp[1][0])); \
        asm volatile("v_permlane32_swap_b32 %0, %1\ns_nop 1" : "+v"(Wp[0][1]), "+v"(Wp[1][1])); \
        asm volatile("v_permlane32_swap_b32 %0, %1\ns_nop 1" : "+v"(Wp[2][0]), "+v"(Wp[3][0])); \
        asm volatile("v_permlane32_swap_b32 %0, %1\ns_nop 1" : "+v"(Wp[2][1]), "+v"(Wp[3][1])); \
        union UW_ { unsigned u[4]; short8 s; } u0_, u1_; \
        u0_.u[0] = Wp[0][0]; u0_.u[1] = Wp[0][1]; u0_.u[2] = Wp[1][0]; u0_.u[3] = Wp[1][1]; \
        u1_.u[0] = Wp[2][0]; u1_.u[1] = Wp[2][1]; u1_.u[2] = Wp[3][0]; u1_.u[3] = Wp[3][1]; \
        ap[mt_][0] = u0_.s; ap[mt_][1] = u1_.s; \
    } \
    __builtin_amdgcn_s_setprio(1); \
    _Pragma("unroll") \
    for (int ks_ = 0; ks_ < 2; ks_++) { \
        const int csw_ = ks_ ? csw1 : csw0; \
        _Pragma("unroll") \
        for (int dt_ = 0; dt_ < 4; dt_++) { \
            short8 bv = *(const short8*)&kv[CB][1][(16 * dt_ + c) * 64 + csw_]; \
            oacc[0][dt_] = __builtin_amdgcn_mfma_f32_16x16x32_bf16(ap[0][ks_], bv, oacc[0][dt_], 0, 0, 0); \
            oacc[1][dt_] = __builtin_amdgcn_mfma_f32_16x16x32_bf16(ap[1][ks_], bv, oacc[1][dt_], 0, 0, 0); \
        } \
    } \
    __builtin_amdgcn_s_setprio(0); \
} while (0)

    if (nkt > 0) STAGE(0, j);
    __syncthreads();                             // tile 0 staged

    for (int i = 0; i < nkt; i++) {
        const int cb = i & 1;
        const int kt = j + KSPLIT * i;
        const int kt0 = kt * 64;

        // issue next tile's DMA FIRST (overlaps this tile's compute)
        if (i + 1 < nkt) STAGE(cb ^ 1, kt + KSPLIT);

        // wave-uniform skip: tile entirely above this wave's diagonal
        if (kt0 <= qrow + 31) {
            if (kt >= 4 * qt) {
                TILE(cb, 1);                     // diagonal region: mask
            } else {
                TILE(cb, 0);                     // interior: no mask
            }
        }

        __syncthreads();   // ONE barrier/tile: drains DMA, closes compute
    }
#undef TILE
#undef STAGE

    // ---- epilogue: sum l over the 4 quads, write bf16 unnormalized partials
    l[0] += __shfl_xor(l[0], 16); l[0] += __shfl_xor(l[0], 32);
    l[1] += __shfl_xor(l[1], 16); l[1] += __shfl_xor(l[1], 32);

    unsigned short* __restrict__ Oj = Opart + (size_t)j * MM * HS;
    #pragma unroll
    for (int mt = 0; mt < 2; mt++)
        #pragma unroll
        for (int dt = 0; dt < 4; dt++)
            #pragma unroll
            for (int reg = 0; reg < 4; reg++)
                Oj[(size_t)(b * TT + qrow + 16 * mt + quad * 4 + reg) * HS + 16 * dt + c] = f2bf(oacc[mt][dt][reg]);
    if (lane < 16) {
        lpart[(size_t)j * MM + b * TT + qrow + lane]      = l[0];
        lpart[(size_t)j * MM + b * TT + qrow + 16 + lane] = l[1];
    }
}

// ---------------------------------------------------------------------------
// combine: out = (sum_j O_j) / (sum_j l_j), j=0..7; O_j stored bf16.
// Thread handles 8 consecutive d (16B bf16 read per j, 32B fp32 write).
// Grid 512 x 256. bf16->fp32 is exact (u<<16); sums in fp32.
// ---------------------------------------------------------------------------
__global__ __launch_bounds__(256) void combine_kernel(
    const unsigned short* __restrict__ Opart, const float* __restrict__ lpart,
    float* __restrict__ out)
{
    const int id = blockIdx.x * 256 + threadIdx.x;   // 0 .. MM*HS/8-1
    const int row = id >> 3;
    const int d0 = (id & 7) * 8;
    float l = 0.f;
    #pragma unroll
    for (int j = 0; j < KSPLIT; j++) l += lpart[(size_t)j * MM + row];
    const size_t stride = (size_t)MM * HS;
    const size_t base = (size_t)row * HS + d0;
    float acc[8] = {0.f, 0.f, 0.f, 0.f, 0.f, 0.f, 0.f, 0.f};
    #pragma unroll
    for (int j = 0; j < KSPLIT; j++) {
        short8 v = *(const short8*)(Opart + (size_t)j * stride + base);
        #pragma unroll
        for (int k = 0; k < 8; k++) {
            union { unsigned u; float f; } cv;
            cv.u = ((unsigned)(unsigned short)v[k]) << 16;   // bf16->f32 exact
            acc[k] += cv.f;
        }
    }
    const float inv = 1.f / l;
    float4 r0 = { acc[0] * inv, acc[1] * inv, acc[2] * inv, acc[3] * inv };
    float4 r1 = { acc[4] * inv, acc[5] * inv, acc[6] * inv, acc[7] * inv };
    *(float4*)(out + base) = r0;
    *(float4*)(out + base + 4) = r1;
}

extern "C" void kernel_launch(void* const* d_in, const int* in_sizes, int n_in,
                              void* d_out, int out_size, void* d_ws, size_t ws_size,
                              hipStream_t stream) {
    const float* x  = (const float*)d_in[0];
    const float* Wq = (const float*)d_in[1];
    const float* Wk = (const float*)d_in[2];
    const float* Wv = (const float*)d_in[3];
    float* out = (float*)d_out;

    unsigned short* Wt   = (unsigned short*)d_ws;            // 384 KB (swizzled)
    unsigned short* qbuf = Wt + 3 * 64 * 1024;               // 2 MB each
    unsigned short* kbt  = qbuf + (size_t)MM * HS;           // tiled+swizzled K
    unsigned short* vTt  = kbt + (size_t)MM * HS;            // tiled+swizzled+permuted V^T
    unsigned short* Opart = vTt + (size_t)MM * HS;           // 8 x 2 MB (bf16)
    float* lpart = (float*)(Opart + (size_t)KSPLIT * MM * HS);  // 512 KB

    prep_kernel<<<48, 256, 0, stream>>>(Wq, Wk, Wv, Wt);
    qkv_mfma<<<MM / 32, 256, 0, stream>>>(x, Wt, qbuf, kbt, vTt);
    attn_mfma<<<BB * (TT / 256) * KSPLIT, 512, 0, stream>>>(qbuf, kbt, vTt, Opart, lpart);
    combine_kernel<<<MM * HS / 8 / 256, 256, 0, stream>>>(Opart, lpart, out);
}